// Round 5
// baseline (326.962 us; speedup 1.0000x reference)
//
#include <hip/hip_runtime.h>

// NavierStokesLossMAC: B=8, H=W=1024
//   d_in[0] v_old (B,2,H,W) f32 | d_in[1] v_new (B,2,H,W) f32
//   d_in[2] p_new (B,1,H,W) f32 | d_in[3] mask  (B,1,H,W) i32
// out: (B,) f32
//
// R5: rolling-window. R4 hit 3.2 TB/s flat despite 65% occupancy -> limit is
// request traffic: single-row blocks request ~15.25 rows per output row
// (~490MB requested vs 245MB HBM), y-halos re-requested by blocks on OTHER
// XCDs (miss local L2). Fix: each block does ROWS=7 consecutive rows, y-reuse
// in registers (7.3 rows requested/row, 2.1x less), x-edges via __shfl +
// 1-lane predicated loads at wave seams (no 64-line strided gathers).
// Stage 2 unchanged: plain stores to ws, 8-block reduce (no atomics: R2
// showed same-line atomicAdd = ~125us serialized cross-XCD write-backs).

#define NS_H 1024
#define NS_W 1024
#define ROWS 7
#define STRIPS ((NS_H - 2) / ROWS)   // 146, exact: 146*7 = 1022

__device__ __forceinline__ float4 ld4(const float* p) { return *(const float4*)p; }
__device__ __forceinline__ float4 avg4(float4 a, float4 b) {
    return make_float4(0.5f*(a.x+b.x), 0.5f*(a.y+b.y), 0.5f*(a.z+b.z), 0.5f*(a.w+b.w));
}
__device__ __forceinline__ float4 sub4(float4 a, float4 b) {
    return make_float4(a.x-b.x, a.y-b.y, a.z-b.z, a.w-b.w);
}

__global__ __launch_bounds__(256, 4) void ns_loss_partial(
    const float* __restrict__ v_old,
    const float* __restrict__ v_new,
    const float* __restrict__ p,
    const int*   __restrict__ mask,
    float* __restrict__ ws)
{
    const int blk = blockIdx.x;
    const int b  = blk / STRIPS;
    const int rb = blk % STRIPS;
    const int y0 = 1 + rb * ROWS;

    const size_t hw = (size_t)NS_H * NS_W;
    const float* uo = v_old + (size_t)b * 2 * hw;
    const float* wo = uo + hw;
    const float* un = v_new + (size_t)b * 2 * hw;
    const float* wn = un + hw;
    const float* pb = p    + (size_t)b * hw;
    const int*   mb = mask + (size_t)b * hw;

    const int tid  = (int)threadIdx.x;
    const int x0   = tid * 4;
    const int lane = tid & 63;

    // ---- prologue: rows y0-1 (as y-) and y0 (as center) ----
    const int r_m = (y0 - 1) * NS_W;
    const int r_c = y0 * NS_W;

    float4 a, bb, c, d;
    a = ld4(un + r_m + x0); bb = ld4(uo + r_m + x0);
    c = ld4(wn + r_m + x0); d  = ld4(wo + r_m + x0);
    float4 u_m = avg4(a, bb), w_m = avg4(c, d);

    a = ld4(un + r_c + x0); bb = ld4(uo + r_c + x0);
    c = ld4(wn + r_c + x0); d  = ld4(wo + r_c + x0);
    float4 u_c = avg4(a, bb), w_c = avg4(c, d);
    float4 du_c = sub4(a, bb), dw_c = sub4(c, d);

    float ul_c = __shfl_up(u_c.w, 1);
    float wl_c = __shfl_up(w_c.w, 1);
    if (lane == 0 && x0 > 0) {
        ul_c = 0.5f * (un[r_c + x0 - 1] + uo[r_c + x0 - 1]);
        wl_c = 0.5f * (wn[r_c + x0 - 1] + wo[r_c + x0 - 1]);
    }
    float ur_c = __shfl_down(u_c.x, 1);
    float wr_c = __shfl_down(w_c.x, 1);
    if (lane == 63 && x0 < NS_W - 4) {
        ur_c = 0.5f * (un[r_c + x0 + 4] + uo[r_c + x0 + 4]);
        wr_c = 0.5f * (wn[r_c + x0 + 4] + wo[r_c + x0 + 4]);
    }
    float4 p_m = ld4(pb + r_m + x0);

    float acc = 0.f;

    #pragma unroll
    for (int r = 0; r < ROWS; ++r) {
        const int rc = (y0 + r) * NS_W;
        const int rp = rc + NS_W;

        // loads for this iteration: velocity row y+1, p & mask row y
        a = ld4(un + rp + x0); bb = ld4(uo + rp + x0);
        c = ld4(wn + rp + x0); d  = ld4(wo + rp + x0);
        float4 pc4 = ld4(pb + rc + x0);
        int4   m4  = *(const int4*)(mb + rc + x0);

        float4 u_p = avg4(a, bb), w_p = avg4(c, d);
        float4 du_p = sub4(a, bb), dw_p = sub4(c, d);

        // edges for the freshly loaded row (used when it becomes center)
        float ul_p = __shfl_up(u_p.w, 1);
        float wl_p = __shfl_up(w_p.w, 1);
        if (lane == 0 && x0 > 0) {
            ul_p = 0.5f * (un[rp + x0 - 1] + uo[rp + x0 - 1]);
            wl_p = 0.5f * (wn[rp + x0 - 1] + wo[rp + x0 - 1]);
        }
        float ur_p = __shfl_down(u_p.x, 1);
        float wr_p = __shfl_down(w_p.x, 1);
        if (lane == 63 && x0 < NS_W - 4) {
            ur_p = 0.5f * (un[rp + x0 + 4] + uo[rp + x0 + 4]);
            wr_p = 0.5f * (wn[rp + x0 + 4] + wo[rp + x0 + 4]);
        }
        float pl = __shfl_up(pc4.w, 1);
        if (lane == 0 && x0 > 0) pl = pb[rc + x0 - 1];

        // ---- compute row y0+r ----
        const float uc[6]  = {ul_c, u_c.x, u_c.y, u_c.z, u_c.w, ur_c};
        const float wcv[6] = {wl_c, w_c.x, w_c.y, w_c.z, w_c.w, wr_c};
        const float uym[4] = {u_m.x, u_m.y, u_m.z, u_m.w};
        const float uyp[4] = {u_p.x, u_p.y, u_p.z, u_p.w};
        const float wym[4] = {w_m.x, w_m.y, w_m.z, w_m.w};
        const float wyp[4] = {w_p.x, w_p.y, w_p.z, w_p.w};
        const float du[4]  = {du_c.x, du_c.y, du_c.z, du_c.w};
        const float dw[4]  = {dw_c.x, dw_c.y, dw_c.z, dw_c.w};
        const float pcv[5] = {pl, pc4.x, pc4.y, pc4.z, pc4.w};
        const float pym[4] = {p_m.x, p_m.y, p_m.z, p_m.w};
        const int   mm[4]  = {m4.x, m4.y, m4.z, m4.w};

        #pragma unroll
        for (int j = 0; j < 4; ++j) {
            const int x = x0 + j;
            const float m = (x >= 1 && x <= NS_W - 2) ? (float)mm[j] : 0.f;

            const float u_cc = uc[j+1],  u_xm = uc[j],  u_xp = uc[j+2];
            const float w_cc = wcv[j+1], w_xm = wcv[j], w_xp = wcv[j+2];

            float res_x =
                dw[j] * 0.25f
              + w_cc * 0.5f * (w_xp - w_xm)
              + 0.5f * ( 0.5f * (u_cc + u_xm) * (w_cc   - wym[j])
                       + 0.5f * (u_cc + u_xp) * (wyp[j] - w_cc  ) )
              + (pcv[j+1] - pcv[j])
              - 0.1f * (w_xm + w_xp + wym[j] + wyp[j] - 4.f * w_cc);

            float res_y =
                du[j] * 0.25f
              + u_cc * 0.5f * (uyp[j] - uym[j])
              + 0.5f * ( 0.5f * (w_cc + wym[j]) * (u_cc - u_xm)
                       + 0.5f * (w_cc + wyp[j]) * (u_xp - u_cc) )
              + (pcv[j+1] - pym[j])
              - 0.1f * (u_xm + u_xp + uym[j] + uyp[j] - 4.f * u_cc);

            acc += m * (res_x * res_x + res_y * res_y);
        }

        // ---- roll the window ----
        u_m = u_c;  u_c = u_p;  ul_c = ul_p;  ur_c = ur_p;
        w_m = w_c;  w_c = w_p;  wl_c = wl_p;  wr_c = wr_p;
        du_c = du_p; dw_c = dw_p;
        p_m = pc4;
    }

    // ---- block reduction: wave shuffle -> 16B LDS -> one plain store ----
    #pragma unroll
    for (int off = 32; off > 0; off >>= 1)
        acc += __shfl_down(acc, off);

    __shared__ float smem[4];
    const int wid = tid >> 6;
    if (lane == 0) smem[wid] = acc;
    __syncthreads();

    if (tid == 0)
        ws[blk] = smem[0] + smem[1] + smem[2] + smem[3];
}

__global__ __launch_bounds__(256) void ns_loss_reduce(
    const float* __restrict__ ws, float* __restrict__ out)
{
    const int b = blockIdx.x;
    float acc = 0.f;
    for (int i = threadIdx.x; i < STRIPS; i += 256)
        acc += ws[b * STRIPS + i];

    #pragma unroll
    for (int off = 32; off > 0; off >>= 1)
        acc += __shfl_down(acc, off);

    __shared__ float smem[4];
    const int lane = threadIdx.x & 63;
    const int wid  = threadIdx.x >> 6;
    if (lane == 0) smem[wid] = acc;
    __syncthreads();

    if (threadIdx.x == 0) {
        const float inv = 1.0f / ((float)(NS_H - 2) * (float)(NS_W - 2));
        out[b] = (smem[0] + smem[1] + smem[2] + smem[3]) * inv;
    }
}

extern "C" void kernel_launch(void* const* d_in, const int* in_sizes, int n_in,
                              void* d_out, int out_size, void* d_ws, size_t ws_size,
                              hipStream_t stream) {
    const float* v_old = (const float*)d_in[0];
    const float* v_new = (const float*)d_in[1];
    const float* p_new = (const float*)d_in[2];
    const int*   msk   = (const int*)d_in[3];
    float* out = (float*)d_out;
    float* ws  = (float*)d_ws;

    const int B = out_size;   // 8

    ns_loss_partial<<<dim3(B * STRIPS), dim3(256), 0, stream>>>(v_old, v_new, p_new, msk, ws);
    ns_loss_reduce<<<dim3(B), dim3(256), 0, stream>>>(ws, out);
}

// Round 6
// 202.565 us; speedup vs baseline: 1.6141x; 1.6141x over previous
//
#include <hip/hip_runtime.h>

// NavierStokesLossMAC: B=8, H=W=1024
//   d_in[0] v_old (B,2,H,W) f32 | d_in[1] v_new (B,2,H,W) f32
//   d_in[2] p_new (B,1,H,W) f32 | d_in[3] mask  (B,1,H,W) i32
// out: (B,) f32
//
// R6 = R5 rolling-window with the two R5 bugs fixed:
//  * NO __launch_bounds__ min-waves arg: (256,4) clamped VGPR to 64 and spilled
//    ~253MB to scratch (WRITE_SIZE 0.25->253MB, VALUBusy 5%). Window needs
//    ~100 VGPR; R4 proved occupancy 23%..65% doesn't change BW, so low
//    occupancy is acceptable.
//  * Direct scalar edge loads (L1 hits, as in R4) instead of shfl+predication.
// Each block: ROWS=7 consecutive interior rows, y-reuse in registers
// (requested traffic ~29KB/row vs R4's 60KB -> ~2x less L2/fabric traffic).
// Stage 2: plain stores to ws + 8-block reduce (R2: same-line atomicAdd
// serializes ~15ns/block of cross-XCD write-backs).

#define NS_H 1024
#define NS_W 1024
#define ROWS 7
#define STRIPS ((NS_H - 2) / ROWS)   // 146 * 7 = 1022 exactly

__device__ __forceinline__ float4 ld4(const float* p) { return *(const float4*)p; }
__device__ __forceinline__ float4 avg4(float4 a, float4 b) {
    return make_float4(0.5f*(a.x+b.x), 0.5f*(a.y+b.y), 0.5f*(a.z+b.z), 0.5f*(a.w+b.w));
}
__device__ __forceinline__ float4 sub4(float4 a, float4 b) {
    return make_float4(a.x-b.x, a.y-b.y, a.z-b.z, a.w-b.w);
}

__global__ __launch_bounds__(256) void ns_loss_partial(
    const float* __restrict__ v_old,
    const float* __restrict__ v_new,
    const float* __restrict__ p,
    const int*   __restrict__ mask,
    float* __restrict__ ws)
{
    const int blk = blockIdx.x;
    const int b  = blk / STRIPS;
    const int rb = blk % STRIPS;
    const int y0 = 1 + rb * ROWS;

    const size_t hw = (size_t)NS_H * NS_W;
    const float* uo = v_old + (size_t)b * 2 * hw;
    const float* wo = uo + hw;
    const float* un = v_new + (size_t)b * 2 * hw;
    const float* wn = un + hw;
    const float* pb = p    + (size_t)b * hw;
    const int*   mb = mask + (size_t)b * hw;

    const int tid = (int)threadIdx.x;
    const int x0  = tid * 4;
    const bool has_r = (x0 + 4 < NS_W);   // last thread's right edge is OOB; value feeds masked x=1023

    // ---- prologue: row y0-1 (y-minus) and row y0 (center) ----
    const int r_m = (y0 - 1) * NS_W;
    const int r_c = y0 * NS_W;

    float4 a, bb, c, d;
    a = ld4(un + r_m + x0); bb = ld4(uo + r_m + x0);
    c = ld4(wn + r_m + x0); d  = ld4(wo + r_m + x0);
    float4 u_m = avg4(a, bb), w_m = avg4(c, d);

    a = ld4(un + r_c + x0); bb = ld4(uo + r_c + x0);
    c = ld4(wn + r_c + x0); d  = ld4(wo + r_c + x0);
    float4 u_c = avg4(a, bb), w_c = avg4(c, d);
    float4 du_c = sub4(a, bb), dw_c = sub4(c, d);

    // edges for center row (left always in-bounds: r_c >= NS_W)
    float ul_c = 0.5f * (un[r_c + x0 - 1] + uo[r_c + x0 - 1]);
    float wl_c = 0.5f * (wn[r_c + x0 - 1] + wo[r_c + x0 - 1]);
    float ur_c = 0.f, wr_c = 0.f;
    if (has_r) {
        ur_c = 0.5f * (un[r_c + x0 + 4] + uo[r_c + x0 + 4]);
        wr_c = 0.5f * (wn[r_c + x0 + 4] + wo[r_c + x0 + 4]);
    }
    float4 p_m = ld4(pb + r_m + x0);

    float acc = 0.f;

    #pragma unroll
    for (int r = 0; r < ROWS; ++r) {
        const int rc = (y0 + r) * NS_W;
        const int rp = rc + NS_W;

        // loads for this iteration: velocity row y+1 (+edges), p & mask row y
        a = ld4(un + rp + x0); bb = ld4(uo + rp + x0);
        c = ld4(wn + rp + x0); d  = ld4(wo + rp + x0);
        float4 pc4 = ld4(pb + rc + x0);
        int4   m4  = *(const int4*)(mb + rc + x0);
        float  pl  = pb[rc + x0 - 1];

        float ul_p = 0.5f * (un[rp + x0 - 1] + uo[rp + x0 - 1]);
        float wl_p = 0.5f * (wn[rp + x0 - 1] + wo[rp + x0 - 1]);
        float ur_p = 0.f, wr_p = 0.f;
        if (has_r) {
            ur_p = 0.5f * (un[rp + x0 + 4] + uo[rp + x0 + 4]);
            wr_p = 0.5f * (wn[rp + x0 + 4] + wo[rp + x0 + 4]);
        }

        float4 u_p = avg4(a, bb), w_p = avg4(c, d);
        float4 du_p = sub4(a, bb), dw_p = sub4(c, d);

        // ---- compute row y0+r ----
        const float uc[6]  = {ul_c, u_c.x, u_c.y, u_c.z, u_c.w, ur_c};
        const float wcv[6] = {wl_c, w_c.x, w_c.y, w_c.z, w_c.w, wr_c};
        const float uym[4] = {u_m.x, u_m.y, u_m.z, u_m.w};
        const float uyp[4] = {u_p.x, u_p.y, u_p.z, u_p.w};
        const float wym[4] = {w_m.x, w_m.y, w_m.z, w_m.w};
        const float wyp[4] = {w_p.x, w_p.y, w_p.z, w_p.w};
        const float du[4]  = {du_c.x, du_c.y, du_c.z, du_c.w};
        const float dw[4]  = {dw_c.x, dw_c.y, dw_c.z, dw_c.w};
        const float pcv[5] = {pl, pc4.x, pc4.y, pc4.z, pc4.w};
        const float pym[4] = {p_m.x, p_m.y, p_m.z, p_m.w};
        const int   mm[4]  = {m4.x, m4.y, m4.z, m4.w};

        #pragma unroll
        for (int j = 0; j < 4; ++j) {
            const int x = x0 + j;
            const float m = (x >= 1 && x <= NS_W - 2) ? (float)mm[j] : 0.f;

            const float u_cc = uc[j+1],  u_xm = uc[j],  u_xp = uc[j+2];
            const float w_cc = wcv[j+1], w_xm = wcv[j], w_xp = wcv[j+2];

            float res_x =
                dw[j] * 0.25f
              + w_cc * 0.5f * (w_xp - w_xm)
              + 0.5f * ( 0.5f * (u_cc + u_xm) * (w_cc   - wym[j])
                       + 0.5f * (u_cc + u_xp) * (wyp[j] - w_cc  ) )
              + (pcv[j+1] - pcv[j])
              - 0.1f * (w_xm + w_xp + wym[j] + wyp[j] - 4.f * w_cc);

            float res_y =
                du[j] * 0.25f
              + u_cc * 0.5f * (uyp[j] - uym[j])
              + 0.5f * ( 0.5f * (w_cc + wym[j]) * (u_cc - u_xm)
                       + 0.5f * (w_cc + wyp[j]) * (u_xp - u_cc) )
              + (pcv[j+1] - pym[j])
              - 0.1f * (u_xm + u_xp + uym[j] + uyp[j] - 4.f * u_cc);

            acc += m * (res_x * res_x + res_y * res_y);
        }

        // ---- roll the window ----
        u_m = u_c;  u_c = u_p;  ul_c = ul_p;  ur_c = ur_p;
        w_m = w_c;  w_c = w_p;  wl_c = wl_p;  wr_c = wr_p;
        du_c = du_p; dw_c = dw_p;
        p_m = pc4;
    }

    // ---- block reduction: wave shuffle -> 16B LDS -> one plain store ----
    #pragma unroll
    for (int off = 32; off > 0; off >>= 1)
        acc += __shfl_down(acc, off);

    __shared__ float smem[4];
    const int lane = tid & 63;
    const int wid  = tid >> 6;
    if (lane == 0) smem[wid] = acc;
    __syncthreads();

    if (tid == 0)
        ws[blk] = smem[0] + smem[1] + smem[2] + smem[3];
}

__global__ __launch_bounds__(256) void ns_loss_reduce(
    const float* __restrict__ ws, float* __restrict__ out)
{
    const int b = blockIdx.x;
    float acc = 0.f;
    for (int i = threadIdx.x; i < STRIPS; i += 256)
        acc += ws[b * STRIPS + i];

    #pragma unroll
    for (int off = 32; off > 0; off >>= 1)
        acc += __shfl_down(acc, off);

    __shared__ float smem[4];
    const int lane = threadIdx.x & 63;
    const int wid  = threadIdx.x >> 6;
    if (lane == 0) smem[wid] = acc;
    __syncthreads();

    if (threadIdx.x == 0) {
        const float inv = 1.0f / ((float)(NS_H - 2) * (float)(NS_W - 2));
        out[b] = (smem[0] + smem[1] + smem[2] + smem[3]) * inv;
    }
}

extern "C" void kernel_launch(void* const* d_in, const int* in_sizes, int n_in,
                              void* d_out, int out_size, void* d_ws, size_t ws_size,
                              hipStream_t stream) {
    const float* v_old = (const float*)d_in[0];
    const float* v_new = (const float*)d_in[1];
    const float* p_new = (const float*)d_in[2];
    const int*   msk   = (const int*)d_in[3];
    float* out = (float*)d_out;
    float* ws  = (float*)d_ws;

    const int B = out_size;   // 8

    ns_loss_partial<<<dim3(B * STRIPS), dim3(256), 0, stream>>>(v_old, v_new, p_new, msk, ws);
    ns_loss_reduce<<<dim3(B), dim3(256), 0, stream>>>(ws, out);
}